// Round 11
// baseline (108.871 us; speedup 1.0000x reference)
//
#include <hip/hip_runtime.h>
#include <stdint.h>

// out[b,j,:] = sym[b,j,:] + sum_{i!=j} (sym[b,i,:] @ W[rel(i,j)].T + bias[rel(i,j)])
// B=8, N=1024, D=128, 6 relations.
//
// Linearity rewrite: agg[j] = sum_r S_r(j) @ W[r].T + cnt_r(j)*bias[r],
//   S_r(j) = sum_{i!=j, rel=r} sym[i];  S_5 derived: S_5 = (allsum - sym_j) - sum_{r<5} S_r.
//  1. prep: symT bf16 [8][128 e][1024 i]; WtB bf16 [kb(24)][e'(128)][kc(32)];
//     allsumF[b][e] = sum_i bf16(X[b][i][e]) in fp32.
//  2. fused (512 thr = 8 e-waves): classify -> masked MFMA (5 accs, DMA-staged
//     symT chunks) -> S5 derive -> S @ Wt (full-K per wave) -> + sym + cnt*bias.
//
// R11: R10 still hovered at the 52-VGPR cap (partial spills). acc 6->5 (-4 regs,
// -17% ph2 MFMA), goff cache dropped (-4), phase-3 full-K (no partial buffer).

typedef __attribute__((ext_vector_type(8))) short bf16x8;
typedef __attribute__((ext_vector_type(4))) float f32x4;
union U4B { uint4 u; bf16x8 b; };

#if defined(__has_builtin)
#  if __has_builtin(__builtin_amdgcn_global_load_lds)
#    define HAVE_GLL 1
#  endif
#  if __has_builtin(__builtin_amdgcn_mul_u24)
#    define OH_MUL24 1
#  endif
#endif

__device__ __forceinline__ uint16_t f2bf(float f) {
    union { float f; uint32_t u; } v; v.f = f;
    uint32_t u = v.u;
    uint32_t r = (u + 0x7FFFu + ((u >> 16) & 1u)) >> 16;  // RNE
    return (uint16_t)r;
}
__device__ __forceinline__ float bfv(uint32_t bits) {   // float from bf16 bits<<16
    union { uint32_t u; float f; } v; v.u = bits; return v.f;
}

// ---------------------------------------------------------------------------
// prep: blk<256: transpose X -> symT[b][e][i] bf16; blk<352: W -> WtB blocked;
//       blk>=352: allsumF[b][e] = sum_i fp32(bf16(X[b][i][e]))  (8 blocks)
// ---------------------------------------------------------------------------
__global__ __launch_bounds__(256)
void prep_kernel(const float* __restrict__ X, const float* __restrict__ W,
                 uint16_t* __restrict__ symT, uint16_t* __restrict__ WtB,
                 float* __restrict__ allsumF) {
    const int blk = blockIdx.x, tid = threadIdx.x;
    __shared__ float T[64 * 65];
    if (blk < 256) {
        const int b = blk & 7, z = blk >> 3, it = z & 15, et = z >> 4;
        const int i0 = it * 64, e0 = et * 64;
        const float4* Xf = (const float4*)X;
#pragma unroll
        for (int s = 0; s < 4; ++s) {
            int il = s * 16 + (tid >> 4), e4 = tid & 15;
            float4 v = Xf[((size_t)b << 15) + (size_t)((i0 + il) << 5) + (e0 >> 2) + e4];
            T[il * 65 + e4 * 4 + 0] = v.x;
            T[il * 65 + e4 * 4 + 1] = v.y;
            T[il * 65 + e4 * 4 + 2] = v.z;
            T[il * 65 + e4 * 4 + 3] = v.w;
        }
        __syncthreads();
#pragma unroll
        for (int s = 0; s < 4; ++s) {
            int el = s * 16 + (tid >> 4), il4 = tid & 15;
            uint16_t h0 = f2bf(T[(il4 * 4 + 0) * 65 + el]);
            uint16_t h1 = f2bf(T[(il4 * 4 + 1) * 65 + el]);
            uint16_t h2 = f2bf(T[(il4 * 4 + 2) * 65 + el]);
            uint16_t h3 = f2bf(T[(il4 * 4 + 3) * 65 + el]);
            uint2 pk = { (uint32_t)h0 | ((uint32_t)h1 << 16),
                         (uint32_t)h2 | ((uint32_t)h3 << 16) };
            *(uint2*)&symT[((size_t)b << 17) + ((size_t)(e0 + el) << 10) + i0 + il4 * 4] = pk;
        }
    } else if (blk < 352) {
        int g = (blk - 256) * 256 + tid;          // 0..24575 float4s of W
        float4 v = ((const float4*)W)[g];
        int r = g >> 12, rem = g & 4095, ep = rem >> 5, e4 = rem & 31;
        int kb = r * 4 + (e4 >> 3);
        int kc = (e4 & 7) * 4;
        uint16_t h0 = f2bf(v.x), h1 = f2bf(v.y), h2 = f2bf(v.z), h3 = f2bf(v.w);
        uint2 pk = { (uint32_t)h0 | ((uint32_t)h1 << 16),
                     (uint32_t)h2 | ((uint32_t)h3 << 16) };
        *(uint2*)&WtB[((size_t)(kb * 128 + ep)) * 32 + kc] = pk;
    } else {
        const int b = blk - 352;                  // 0..7
        const int e = tid & 127, ih = tid >> 7;
        const float* Xb = X + ((size_t)b << 17);
        float s = 0.f;
#pragma unroll 4
        for (int i = ih * 512; i < ih * 512 + 512; ++i) {
            float v = Xb[((size_t)i << 7) + e];
            s += bfv((uint32_t)f2bf(v) << 16);    // sum the bf16-rounded values
        }
        if (ih == 1) T[e] = s;
        __syncthreads();
        if (ih == 0) allsumF[b * 128 + e] = s + T[e];
    }
}

// ---------------------------------------------------------------------------
// fused kernel: grid 512 = 8b x 64jt (16 j per block), 512 thr = 8 e-waves.
// LDS (81920 B -> 2 blocks/CU):
//   @0     symTS[2] 32768 each (16B segs XOR-swizzled seg^=(e&15));
//          buf1 overlays posS during classify; after phase 2 region holds
//          SA (24704 B @0, pitch 776 hw) + ctile (8448 B @24832)
//   @65536 rel32: 16 j x 256 dw, dword-pair swizzle (idx ^ 2m), 16384 B
// ---------------------------------------------------------------------------
#define SP 776

__global__ __launch_bounds__(512)
void fused_kernel(const float* __restrict__ sym, const float* __restrict__ pos,
                  const uint16_t* __restrict__ symT, const uint16_t* __restrict__ WtB,
                  const float* __restrict__ bias, const float* __restrict__ allsumF,
                  float* __restrict__ out) {
    __shared__ __align__(16) char smem[81920];
    uint16_t* SA     = (uint16_t*)smem;
    float*    ctile  = (float*)(smem + 24832);
    float2*   posS   = (float2*)(smem + 32768);
    uint32_t* rel32  = (uint32_t*)(smem + 65536);

    const int blk = blockIdx.x;
    const int b = blk & 7, jt = blk >> 3, j0 = jt * 16;
    const int tid = threadIdx.x;
    const int w = tid >> 6, lane = tid & 63, m = lane & 15, q = lane >> 4;

    const uint16_t* symTb = symT + ((size_t)b << 17);

    auto issue_chunk = [&](int cidx, int bufsel) {
#ifdef HAVE_GLL
#pragma unroll
        for (int s = 0; s < 4; ++s) {
            int c16 = s * 512 + tid;
            int e = c16 >> 4, sg = (c16 & 15) ^ (e & 15);
            const uint16_t* gp = symTb + (e << 10) + cidx * 128 + sg * 8;
            char* lp = smem + bufsel * 32768 + s * 8192 + w * 1024;   // wave-uniform
            typedef const __attribute__((address_space(1))) uint32_t gu32;
            typedef __attribute__((address_space(3))) uint32_t lu32;
            __builtin_amdgcn_global_load_lds((gu32*)gp, (lu32*)lp, 16, 0, 0);
        }
#else
#pragma unroll
        for (int s = 0; s < 4; ++s) {
            int c16 = s * 512 + tid;
            int e = c16 >> 4, sg = (c16 & 15) ^ (e & 15);
            uint4 v = *(const uint4*)(symTb + (e << 10) + cidx * 128 + sg * 8);
            *(uint4*)(smem + bufsel * 32768 + c16 * 16) = v;
        }
#endif
    };

    issue_chunk(0, 0);                      // async into buf0, hidden under classify

    // ---- phase 0: stage positions (buf1 region; dead before buf1's first DMA)
    const float2* pos2 = (const float2*)pos + ((size_t)b << 10);
    posS[tid] = pos2[tid];
    posS[tid + 512] = pos2[tid + 512];
    __syncthreads();

    // ---- phase 1: classify 16 j x 1024 i -> one-hot bytes (0 on diagonal) ----
    {
        const int mm = tid & 15, grp = tid >> 4;    // grp 0..31: 32 i's each
        const int j = j0 + mm;
        const float2 pj = posS[j];
        uint32_t* dst = &rel32[mm * 256];
        const int sw = mm * 2;                      // pair-granular XOR swizzle
#pragma unroll
        for (int s = 0; s < 8; ++s) {
            uint32_t word = 0;
#pragma unroll
            for (int qq = 0; qq < 4; ++qq) {
                int i = grp * 32 + s * 4 + qq;
                float2 pi = posS[i];
                float dx = pj.x - pi.x, dy = pj.y - pi.y;
                // faithful priority chain of _get_relation_type
                int r = (dy > 0.5f) ? 0
                      : (dy < -0.5f) ? 1
                      : (dx < -0.5f) ? 2
                      : (dx > 0.5f)  ? 3
                      : (fabsf(dx) < 0.3f && fabsf(dy) < 0.3f) ? 4
                      : 5;
                uint32_t oh = (i == j) ? 0u : (1u << r);
                word |= oh << (8 * qq);
            }
            dst[(grp * 8 + s) ^ sw] = word;
        }
    }
    __syncthreads();

    // ---- phase 2: masked GEMM, 8 chunks of 128 i, DMA double-buffered ----
    f32x4 acc[5];
#pragma unroll
    for (int r = 0; r < 5; ++r) acc[r] = (f32x4){0.f, 0.f, 0.f, 0.f};

    const int E = w * 16 + m;        // e-row owned by this lane (E&15 == m)
    const int csw = m * 2;

    for (int c = 0; c < 8; ++c) {
        if (c < 7) issue_chunk(c + 1, (c + 1) & 1);
        const uint16_t* bt = (const uint16_t*)(smem + ((c & 1) << 15)) + E * 128;
        const uint32_t* crow = &rel32[m * 256 + c * 32];
#pragma unroll
        for (int ks = 0; ks < 4; ++ks) {
            U4B bfr;
            bfr.u = *(const uint4*)(bt + ((((ks << 2) + q) ^ m) << 3));
            uint2 cw = *(const uint2*)&crow[(((ks << 3) + (q << 1)) ^ csw)];
            // byte -> halfword expansion (shared across r)
            uint32_t hx01 = __builtin_amdgcn_perm(cw.x, cw.x, 0x01010000u) & 0x00FF00FFu;
            uint32_t hx23 = __builtin_amdgcn_perm(cw.x, cw.x, 0x03030202u) & 0x00FF00FFu;
            uint32_t hy01 = __builtin_amdgcn_perm(cw.y, cw.y, 0x01010000u) & 0x00FF00FFu;
            uint32_t hy23 = __builtin_amdgcn_perm(cw.y, cw.y, 0x03030202u) & 0x00FF00FFu;
#pragma unroll
            for (int r = 0; r < 5; ++r) {
                const uint32_t rm = 0x00010001u << r;
                U4B a;
#ifdef OH_MUL24
                const uint32_t mc = 0x3F80u >> r;   // 2^r * mc == 0x3F80 (bf16 1.0)
                a.u.x = (uint32_t)__builtin_amdgcn_mul_u24((int)(hx01 & rm), (int)mc);
                a.u.y = (uint32_t)__builtin_amdgcn_mul_u24((int)(hx23 & rm), (int)mc);
                a.u.z = (uint32_t)__builtin_amdgcn_mul_u24((int)(hy01 & rm), (int)mc);
                a.u.w = (uint32_t)__builtin_amdgcn_mul_u24((int)(hy23 & rm), (int)mc);
#else
                uint32_t g2;
                g2 = hx01 & rm; a.u.x = (g2 << (14 - r)) - (g2 << (7 - r));
                g2 = hx23 & rm; a.u.y = (g2 << (14 - r)) - (g2 << (7 - r));
                g2 = hy01 & rm; a.u.z = (g2 << (14 - r)) - (g2 << (7 - r));
                g2 = hy23 & rm; a.u.w = (g2 << (14 - r)) - (g2 << (7 - r));
#endif
                acc[r] = __builtin_amdgcn_mfma_f32_16x16x32_bf16(a.b, bfr.b, acc[r], 0, 0, 0);
            }
        }
        __syncthreads();   // drains next-chunk DMA + releases read buffer
    }

    // ---- phase 3a: S rows -> SA (bf16); S_5 derived via linearity ----
    {
        uint2 sjv = *(const uint2*)(symTb + ((size_t)E << 10) + j0 + q * 4);
        float asum = allsumF[b * 128 + E];
        float sj[4];
        sj[0] = bfv(sjv.x << 16);
        sj[1] = bfv(sjv.x & 0xFFFF0000u);
        sj[2] = bfv(sjv.y << 16);
        sj[3] = bfv(sjv.y & 0xFFFF0000u);
#pragma unroll
        for (int reg = 0; reg < 4; ++reg) {
            const int row = (q * 4 + reg) * SP;
            float s01 = acc[0][reg] + acc[1][reg];
            float s23 = acc[2][reg] + acc[3][reg];
            float ssum = s01 + s23 + acc[4][reg];
#pragma unroll
            for (int r = 0; r < 5; ++r)
                SA[row + r * 128 + E] = f2bf(acc[r][reg]);
            SA[row + 5 * 128 + E] = f2bf(asum - sj[reg] - ssum);
        }
    }
    __syncthreads();

    // ---- phase 3b: C2 = S @ Wt, full K=768 per wave (wave owns 16 e') ----
    {
        f32x4 c2 = {0.f, 0.f, 0.f, 0.f};
#pragma unroll
        for (int kb = 0; kb < 24; ++kb) {
            U4B af, bw;
            af.u = *(const uint4*)&SA[m * SP + kb * 32 + q * 8];
            bw.u = *(const uint4*)&WtB[(((size_t)(kb * 128 + E)) << 5) + q * 8];
            c2 = __builtin_amdgcn_mfma_f32_16x16x32_bf16(af.b, bw.b, c2, 0, 0, 0);
        }
#pragma unroll
        for (int reg = 0; reg < 4; ++reg)
            ctile[(q * 4 + reg) * 132 + E] = c2[reg];
    }
    __syncthreads();

    // ---- epilogue: ctile + sym + cnt_r*bias (counts recomputed from rel32) ----
    {
        const int j = tid >> 5, t = tid & 31, e0 = t * 4;
        const uint32_t* row = &rel32[j * 256];
        uint4 ra = *(const uint4*)&row[t * 8];
        uint4 rb = *(const uint4*)&row[t * 8 + 4];
        uint32_t s0 = 0, s1 = 0, s2 = 0, s3 = 0, s4 = 0, s5 = 0;
        uint32_t wds[8] = { ra.x, ra.y, ra.z, ra.w, rb.x, rb.y, rb.z, rb.w };
#pragma unroll
        for (int k = 0; k < 8; ++k) {
            uint32_t wd = wds[k];
            s0 += wd & 0x01010101u;        s1 += (wd >> 1) & 0x01010101u;
            s2 += (wd >> 2) & 0x01010101u; s3 += (wd >> 3) & 0x01010101u;
            s4 += (wd >> 4) & 0x01010101u; s5 += (wd >> 5) & 0x01010101u;
        }
        int cnt[6];
        cnt[0] = (int)((s0 * 0x01010101u) >> 24);
        cnt[1] = (int)((s1 * 0x01010101u) >> 24);
        cnt[2] = (int)((s2 * 0x01010101u) >> 24);
        cnt[3] = (int)((s3 * 0x01010101u) >> 24);
        cnt[4] = (int)((s4 * 0x01010101u) >> 24);
        cnt[5] = (int)((s5 * 0x01010101u) >> 24);
#pragma unroll
        for (int off = 1; off < 32; off <<= 1)
#pragma unroll
            for (int r = 0; r < 6; ++r)
                cnt[r] += __shfl_xor(cnt[r], off, 64);   // 32-lane-group reduce

        float4 a4 = *(const float4*)&ctile[j * 132 + e0];
#pragma unroll
        for (int r = 0; r < 6; ++r) {
            float cf = (float)cnt[r];
            float4 bb = *(const float4*)&bias[r * 128 + e0];
            a4.x += cf * bb.x; a4.y += cf * bb.y; a4.z += cf * bb.z; a4.w += cf * bb.w;
        }
        size_t o = ((size_t)(b * 1024 + j0 + j) << 7) + e0;
        float4 sv = *(const float4*)&sym[o];
        float4 ov = { sv.x + a4.x, sv.y + a4.y, sv.z + a4.z, sv.w + a4.w };
        *(float4*)&out[o] = ov;
    }
}

extern "C" void kernel_launch(void* const* d_in, const int* in_sizes, int n_in,
                              void* d_out, int out_size, void* d_ws, size_t ws_size,
                              hipStream_t stream) {
    const float* symbols   = (const float*)d_in[0];  // [8,1024,128]
    const float* positions = (const float*)d_in[1];  // [8,1024,2]
    const float* W         = (const float*)d_in[2];  // [6,128,128]
    const float* bias      = (const float*)d_in[3];  // [6,128]
    float* out             = (float*)d_out;          // [8,1024,128]

    char* ws = (char*)d_ws;
    uint16_t* symT    = (uint16_t*)ws;               // 2,097,152 B
    uint16_t* WtB     = (uint16_t*)(ws + 2097152);   //   196,608 B
    float*    allsumF = (float*)(ws + 2293760);      //     4,096 B

    prep_kernel<<<360, 256, 0, stream>>>(symbols, W, symT, WtB, allsumF);
    fused_kernel<<<512, 512, 0, stream>>>(symbols, positions, symT, WtB, bias,
                                          allsumF, out);
}

// Round 12
// 96.929 us; speedup vs baseline: 1.1232x; 1.1232x over previous
//
#include <hip/hip_runtime.h>
#include <stdint.h>

// out[b,j,:] = sym[b,j,:] + sum_{i!=j} (sym[b,i,:] @ W[rel(i,j)].T + bias[rel(i,j)])
// B=8, N=1024, D=128, 6 relations.
//
// Linearity rewrite:  agg[j] = sum_r (sum_{i!=j, rel=r} sym[i]) @ W[r].T + cnt_r(j)*bias[r]
//  1. prep: symT bf16 [8][128 e][1024 i]; WtB bf16 blocked [kb(24)][e'(128)][kc(32)]
//  2. fused (512 thr = 8 e-waves): classify -> masked MFMA (S_r = M_r @ symT)
//     -> S @ Wt (K=768, 4-way K-split) -> + sym + cnt*bias.
//
// R12: revert R11 (regressed, bundled changes). R10 base + phase 2 split into two
// r-passes with acc[3] (12 VGPRs loop-carried): peak live ~38 << 52-VGPR cap ->
// spills impossible even at the allocator's 8-wave heuristic target. Pass 0
// (r=0..2) double-buffered; its S rows land in SA (overlays buf0), so pass 1
// (r=3..5) runs single-buffered from buf1.

typedef __attribute__((ext_vector_type(8))) short bf16x8;
typedef __attribute__((ext_vector_type(4))) float f32x4;
union U4B { uint4 u; bf16x8 b; };

#if defined(__has_builtin)
#  if __has_builtin(__builtin_amdgcn_global_load_lds)
#    define HAVE_GLL 1
#  endif
#  if __has_builtin(__builtin_amdgcn_mul_u24)
#    define OH_MUL24 1
#  endif
#endif

__device__ __forceinline__ uint16_t f2bf(float f) {
    union { float f; uint32_t u; } v; v.f = f;
    uint32_t u = v.u;
    uint32_t r = (u + 0x7FFFu + ((u >> 16) & 1u)) >> 16;  // RNE
    return (uint16_t)r;
}

// ---------------------------------------------------------------------------
// prep: blocks 0..255: transpose X[b][i][e] fp32 -> symT[b][e][i] bf16 (64x64 tiles)
//       blocks 256..351: W[r][ep][e] fp32 -> WtB[(kb*128+ep)*32+kc] bf16, k=r*128+e
// ---------------------------------------------------------------------------
__global__ __launch_bounds__(256)
void prep_kernel(const float* __restrict__ X, const float* __restrict__ W,
                 uint16_t* __restrict__ symT, uint16_t* __restrict__ WtB) {
    const int blk = blockIdx.x, tid = threadIdx.x;
    if (blk < 256) {
        __shared__ float T[64 * 65];
        const int b = blk & 7, z = blk >> 3, it = z & 15, et = z >> 4;
        const int i0 = it * 64, e0 = et * 64;
        const float4* Xf = (const float4*)X;
#pragma unroll
        for (int s = 0; s < 4; ++s) {
            int il = s * 16 + (tid >> 4), e4 = tid & 15;
            float4 v = Xf[((size_t)b << 15) + (size_t)((i0 + il) << 5) + (e0 >> 2) + e4];
            T[il * 65 + e4 * 4 + 0] = v.x;
            T[il * 65 + e4 * 4 + 1] = v.y;
            T[il * 65 + e4 * 4 + 2] = v.z;
            T[il * 65 + e4 * 4 + 3] = v.w;
        }
        __syncthreads();
#pragma unroll
        for (int s = 0; s < 4; ++s) {
            int el = s * 16 + (tid >> 4), il4 = tid & 15;
            uint16_t h0 = f2bf(T[(il4 * 4 + 0) * 65 + el]);
            uint16_t h1 = f2bf(T[(il4 * 4 + 1) * 65 + el]);
            uint16_t h2 = f2bf(T[(il4 * 4 + 2) * 65 + el]);
            uint16_t h3 = f2bf(T[(il4 * 4 + 3) * 65 + el]);
            uint2 pk = { (uint32_t)h0 | ((uint32_t)h1 << 16),
                         (uint32_t)h2 | ((uint32_t)h3 << 16) };
            *(uint2*)&symT[((size_t)b << 17) + ((size_t)(e0 + el) << 10) + i0 + il4 * 4] = pk;
        }
    } else {
        int g = (blk - 256) * 256 + tid;          // 0..24575 float4s of W
        float4 v = ((const float4*)W)[g];
        int r = g >> 12, rem = g & 4095, ep = rem >> 5, e4 = rem & 31;
        int kb = r * 4 + (e4 >> 3);               // k = r*128 + e4*4+t
        int kc = (e4 & 7) * 4;
        uint16_t h0 = f2bf(v.x), h1 = f2bf(v.y), h2 = f2bf(v.z), h3 = f2bf(v.w);
        uint2 pk = { (uint32_t)h0 | ((uint32_t)h1 << 16),
                     (uint32_t)h2 | ((uint32_t)h3 << 16) };
        *(uint2*)&WtB[((size_t)(kb * 128 + ep)) * 32 + kc] = pk;
    }
}

// ---------------------------------------------------------------------------
// fused kernel: grid 512 = 8b x 64jt (16 j per block), 512 thr = 8 waves.
// LDS map (81920 B -> 2 blocks/CU):
//   @0     symTS[2] double buffer, 32768 B each, 16B segs XOR-swizzled
//          (seg' = seg ^ (e&15)); buf1 doubles as posS during classify;
//          after phase 2: SA (24832 B @0) + partial (33792 B @24832)
//   @65536 rel32: 16 j x 256 dwords, dword-pair swizzle (idx ^ 2m), 16384 B
// ---------------------------------------------------------------------------
#define SP 776

__global__ __launch_bounds__(512)
void fused_kernel(const float* __restrict__ sym, const float* __restrict__ pos,
                  const uint16_t* __restrict__ symT, const uint16_t* __restrict__ WtB,
                  const float* __restrict__ bias, float* __restrict__ out) {
    __shared__ __align__(16) char smem[81920];
    uint16_t* SA      = (uint16_t*)smem;
    float*    partial = (float*)(smem + 24832);
    float2*   posS    = (float2*)(smem + 32768);
    uint32_t* rel32   = (uint32_t*)(smem + 65536);

    const int blk = blockIdx.x;
    const int b = blk & 7, jt = blk >> 3, j0 = jt * 16;
    const int tid = threadIdx.x;
    const int w = tid >> 6, lane = tid & 63, m = lane & 15, q = lane >> 4;

    const uint16_t* symTb = symT + ((size_t)b << 17);

    auto issue_chunk = [&](int cidx, int bufsel) {
#ifdef HAVE_GLL
#pragma unroll
        for (int s = 0; s < 4; ++s) {
            int c16 = s * 512 + tid;
            int e = c16 >> 4, sg = (c16 & 15) ^ (e & 15);
            const uint16_t* gp = symTb + (e << 10) + cidx * 128 + sg * 8;
            char* lp = smem + bufsel * 32768 + s * 8192 + w * 1024;   // wave-uniform
            typedef const __attribute__((address_space(1))) uint32_t gu32;
            typedef __attribute__((address_space(3))) uint32_t lu32;
            __builtin_amdgcn_global_load_lds((gu32*)gp, (lu32*)lp, 16, 0, 0);
        }
#else
#pragma unroll
        for (int s = 0; s < 4; ++s) {
            int c16 = s * 512 + tid;
            int e = c16 >> 4, sg = (c16 & 15) ^ (e & 15);
            uint4 v = *(const uint4*)(symTb + (e << 10) + cidx * 128 + sg * 8);
            *(uint4*)(smem + bufsel * 32768 + c16 * 16) = v;
        }
#endif
    };

    issue_chunk(0, 0);                      // async into buf0, hidden under classify

    // ---- phase 0: stage positions (buf1 region; dead before buf1's first DMA)
    const float2* pos2 = (const float2*)pos + ((size_t)b << 10);
    posS[tid] = pos2[tid];
    posS[tid + 512] = pos2[tid + 512];
    __syncthreads();

    // ---- phase 1: classify 16 j x 1024 i -> one-hot bytes (0 on diagonal) ----
    {
        const int mm = tid & 15, grp = tid >> 4;    // grp 0..31: 32 i's each
        const int j = j0 + mm;
        const float2 pj = posS[j];
        uint32_t* dst = &rel32[mm * 256];
        const int sw = mm * 2;                      // pair-granular XOR swizzle
#pragma unroll
        for (int s = 0; s < 8; ++s) {
            uint32_t word = 0;
#pragma unroll
            for (int qq = 0; qq < 4; ++qq) {
                int i = grp * 32 + s * 4 + qq;
                float2 pi = posS[i];
                float dx = pj.x - pi.x, dy = pj.y - pi.y;
                // faithful priority chain of _get_relation_type
                int r = (dy > 0.5f) ? 0
                      : (dy < -0.5f) ? 1
                      : (dx < -0.5f) ? 2
                      : (dx > 0.5f)  ? 3
                      : (fabsf(dx) < 0.3f && fabsf(dy) < 0.3f) ? 4
                      : 5;
                uint32_t oh = (i == j) ? 0u : (1u << r);
                word |= oh << (8 * qq);
            }
            dst[(grp * 8 + s) ^ sw] = word;
        }
    }
    __syncthreads();

    // ---- phase 2: masked GEMM in two r-passes, acc[3] loop-carried ----
    const int E = w * 16 + m;        // e-row owned by this lane (E&15 == m)
    const int csw = m * 2;

    auto compute_chunk = [&](int d, int buf, int rbase, f32x4* acc) {
        const uint16_t* bt = (const uint16_t*)(smem + (buf << 15)) + E * 128;
        const uint32_t* crow = &rel32[m * 256 + d * 32];
#pragma unroll
        for (int ks = 0; ks < 4; ++ks) {
            U4B bfr;
            bfr.u = *(const uint4*)(bt + ((((ks << 2) + q) ^ m) << 3));
            uint2 cw = *(const uint2*)&crow[(((ks << 3) + (q << 1)) ^ csw)];
            // byte -> halfword expansion (shared across r)
            uint32_t hx01 = __builtin_amdgcn_perm(cw.x, cw.x, 0x01010000u) & 0x00FF00FFu;
            uint32_t hx23 = __builtin_amdgcn_perm(cw.x, cw.x, 0x03030202u) & 0x00FF00FFu;
            uint32_t hy01 = __builtin_amdgcn_perm(cw.y, cw.y, 0x01010000u) & 0x00FF00FFu;
            uint32_t hy23 = __builtin_amdgcn_perm(cw.y, cw.y, 0x03030202u) & 0x00FF00FFu;
#pragma unroll
            for (int rr = 0; rr < 3; ++rr) {
                const int r = rbase + rr;           // call-site-constant -> folds
                const uint32_t rm = 0x00010001u << r;
                U4B a;
#ifdef OH_MUL24
                const uint32_t mc = 0x3F80u >> r;   // 2^r * mc == 0x3F80 (bf16 1.0)
                a.u.x = (uint32_t)__builtin_amdgcn_mul_u24((int)(hx01 & rm), (int)mc);
                a.u.y = (uint32_t)__builtin_amdgcn_mul_u24((int)(hx23 & rm), (int)mc);
                a.u.z = (uint32_t)__builtin_amdgcn_mul_u24((int)(hy01 & rm), (int)mc);
                a.u.w = (uint32_t)__builtin_amdgcn_mul_u24((int)(hy23 & rm), (int)mc);
#else
                uint32_t g2;
                g2 = hx01 & rm; a.u.x = (g2 << (14 - r)) - (g2 << (7 - r));
                g2 = hx23 & rm; a.u.y = (g2 << (14 - r)) - (g2 << (7 - r));
                g2 = hy01 & rm; a.u.z = (g2 << (14 - r)) - (g2 << (7 - r));
                g2 = hy23 & rm; a.u.w = (g2 << (14 - r)) - (g2 << (7 - r));
#endif
                acc[rr] = __builtin_amdgcn_mfma_f32_16x16x32_bf16(a.b, bfr.b, acc[rr], 0, 0, 0);
            }
        }
    };

    f32x4 acc[3];

    // pass 0: r = 0..2, double-buffered buf0/buf1
#pragma unroll
    for (int rr = 0; rr < 3; ++rr) acc[rr] = (f32x4){0.f, 0.f, 0.f, 0.f};
    for (int c = 0; c < 8; ++c) {
        if (c < 7) issue_chunk(c + 1, (c + 1) & 1);
        compute_chunk(c, c & 1, 0, acc);
        __syncthreads();    // drains next-chunk DMA + releases read buffer
    }
    // S_0..2 -> SA (buf0 region; all reads of buf0 done per final barrier)
#pragma unroll
    for (int rr = 0; rr < 3; ++rr)
#pragma unroll
        for (int reg = 0; reg < 4; ++reg)
            SA[(q * 4 + reg) * SP + rr * 128 + E] = f2bf(acc[rr][reg]);

    // pass 1: r = 3..5, single-buffered in buf1 (SA occupies buf0)
#pragma unroll
    for (int rr = 0; rr < 3; ++rr) acc[rr] = (f32x4){0.f, 0.f, 0.f, 0.f};
    for (int c = 0; c < 8; ++c) {
        issue_chunk(c, 1);
        __syncthreads();    // drain DMA before reading
        compute_chunk(c, 1, 3, acc);
        __syncthreads();    // release buf1 for next chunk
    }
#pragma unroll
    for (int rr = 0; rr < 3; ++rr)
#pragma unroll
        for (int reg = 0; reg < 4; ++reg)
            SA[(q * 4 + reg) * SP + (rr + 3) * 128 + E] = f2bf(acc[rr][reg]);
    __syncthreads();

    // ---- phase 3: C2 = S @ Wt, 4-way K-split over wave pairs ----
    {
        const int g = w >> 1, h = w & 1;
        f32x4 c2[4];
#pragma unroll
        for (int nf = 0; nf < 4; ++nf) c2[nf] = (f32x4){0.f, 0.f, 0.f, 0.f};
#pragma unroll
        for (int kf = 0; kf < 6; ++kf) {
            U4B af;
            af.u = *(const uint4*)&SA[m * SP + g * 192 + kf * 32 + q * 8];
            const int kb = g * 6 + kf;
#pragma unroll
            for (int nf = 0; nf < 4; ++nf) {
                U4B bw;
                bw.u = *(const uint4*)&WtB[((size_t)(kb * 128 + h * 64 + nf * 16 + m)) * 32 + q * 8];
                c2[nf] = __builtin_amdgcn_mfma_f32_16x16x32_bf16(af.b, bw.b, c2[nf], 0, 0, 0);
            }
        }
#pragma unroll
        for (int nf = 0; nf < 4; ++nf)
#pragma unroll
            for (int reg = 0; reg < 4; ++reg)
                partial[g * 2112 + (q * 4 + reg) * 132 + h * 64 + nf * 16 + m] = c2[nf][reg];
    }
    __syncthreads();

    // ---- epilogue: reduce K-split partials + sym + cnt_r*bias ----
    // counts recomputed from rel32 (swizzle is a row-internal permutation; sum invariant)
    {
        const int j = tid >> 5, t = tid & 31, e0 = t << 2;
        const uint32_t* row = &rel32[j * 256 + t * 8];
        uint32_t s0 = 0, s1 = 0, s2 = 0, s3 = 0, s4 = 0, s5 = 0;
#pragma unroll
        for (int k = 0; k < 8; ++k) {
            uint32_t wd = row[k];
            s0 += wd & 0x01010101u;        s1 += (wd >> 1) & 0x01010101u;
            s2 += (wd >> 2) & 0x01010101u; s3 += (wd >> 3) & 0x01010101u;
            s4 += (wd >> 4) & 0x01010101u; s5 += (wd >> 5) & 0x01010101u;
        }
        int cnt[6];
        cnt[0] = (int)((s0 * 0x01010101u) >> 24);
        cnt[1] = (int)((s1 * 0x01010101u) >> 24);
        cnt[2] = (int)((s2 * 0x01010101u) >> 24);
        cnt[3] = (int)((s3 * 0x01010101u) >> 24);
        cnt[4] = (int)((s4 * 0x01010101u) >> 24);
        cnt[5] = (int)((s5 * 0x01010101u) >> 24);
#pragma unroll
        for (int off = 1; off < 32; off <<= 1)
#pragma unroll
            for (int r = 0; r < 6; ++r)
                cnt[r] += __shfl_xor(cnt[r], off, 64);   // 32-lane-group reduce

        float4 a4 = {0.f, 0.f, 0.f, 0.f};
#pragma unroll
        for (int g4 = 0; g4 < 4; ++g4) {
            float4 u = *(const float4*)&partial[g4 * 2112 + j * 132 + e0];
            a4.x += u.x; a4.y += u.y; a4.z += u.z; a4.w += u.w;
        }
#pragma unroll
        for (int r = 0; r < 6; ++r) {
            float cf = (float)cnt[r];
            float4 bb = *(const float4*)&bias[r * 128 + e0];
            a4.x += cf * bb.x; a4.y += cf * bb.y; a4.z += cf * bb.z; a4.w += cf * bb.w;
        }
        size_t o = ((size_t)(b * 1024 + j0 + j) << 7) + e0;
        float4 sv = *(const float4*)&sym[o];
        float4 ov = { sv.x + a4.x, sv.y + a4.y, sv.z + a4.z, sv.w + a4.w };
        *(float4*)&out[o] = ov;
    }
}

extern "C" void kernel_launch(void* const* d_in, const int* in_sizes, int n_in,
                              void* d_out, int out_size, void* d_ws, size_t ws_size,
                              hipStream_t stream) {
    const float* symbols   = (const float*)d_in[0];  // [8,1024,128]
    const float* positions = (const float*)d_in[1];  // [8,1024,2]
    const float* W         = (const float*)d_in[2];  // [6,128,128]
    const float* bias      = (const float*)d_in[3];  // [6,128]
    float* out             = (float*)d_out;          // [8,1024,128]

    char* ws = (char*)d_ws;
    uint16_t* symT = (uint16_t*)ws;                  // 8*128*1024 bf16 = 2,097,152 B
    uint16_t* WtB  = (uint16_t*)(ws + 2097152);      // 24*128*32 bf16 =   196,608 B

    prep_kernel<<<352, 256, 0, stream>>>(symbols, W, symT, WtB);
    fused_kernel<<<512, 512, 0, stream>>>(symbols, positions, symT, WtB, bias, out);
}